// Round 1
// baseline (323.872 us; speedup 1.0000x reference)
//
#include <hip/hip_runtime.h>

typedef unsigned short u16;
typedef __attribute__((ext_vector_type(8))) short bf16x8;
typedef __attribute__((ext_vector_type(4))) float f32x4;
typedef __attribute__((ext_vector_type(4))) unsigned short u16x4;

#define MFMA16(a, b, c) __builtin_amdgcn_mfma_f32_16x16x32_bf16((a), (b), (c), 0, 0, 0)

// d_ws layout (u16 element offsets)
#define OFF_WQ   0
#define OFF_WG   65536
#define OFF_WC1  131072
#define OFF_WO   163840
#define OFF_KNF  229376   // normalized fast keys  [h][s][d]
#define OFF_VTF  245760   // fast vals transposed  [h][d][s]
#define OFF_KND  262144
#define OFF_VTD  278528

__device__ __forceinline__ u16 f2b(float f) {
  union { float f; unsigned u; } v; v.f = f;
  unsigned r = v.u + 0x7fffu + ((v.u >> 16) & 1u);  // RNE fp32->bf16
  return (u16)(r >> 16);
}
__device__ __forceinline__ float fsig(float x) {
  return __builtin_amdgcn_rcpf(1.f + __expf(-x));
}
__device__ __forceinline__ float ftanh(float x) {
  float e = __expf(2.f * x);
  return (e - 1.f) * __builtin_amdgcn_rcpf(e + 1.f);
}
__device__ __forceinline__ float sum16(float v) {
  v += __shfl_xor(v, 1);
  v += __shfl_xor(v, 2);
  v += __shfl_xor(v, 4);
  v += __shfl_xor(v, 8);
  return v;
}

// ---------- pre-kernel: weights fp32 -> bf16 ----------
__global__ void k_convert(const float* __restrict__ Wq, const float* __restrict__ Wg,
                          const float* __restrict__ Wc1, const float* __restrict__ Wo,
                          u16* __restrict__ ws) {
  int i = blockIdx.x * 256 + threadIdx.x;  // 65536 threads
  ws[OFF_WQ + i] = f2b(Wq[i]);
  ws[OFF_WG + i] = f2b(Wg[i]);
  ws[OFF_WO + i] = f2b(Wo[i]);
  if (i < 32768) ws[OFF_WC1 + i] = f2b(Wc1[i]);
}

// ---------- pre-kernel: normalize keys, transpose vals ----------
__global__ void k_prep(const float* __restrict__ fk, const float* __restrict__ fv,
                       const float* __restrict__ dk, const float* __restrict__ dv,
                       u16* __restrict__ ws) {
  int t = blockIdx.x * 64 + threadIdx.x;  // t = h*64+s, 0..255
  int h = t >> 6, s = t & 63;
  const float* p;
  float ss, sc;

  p = fk + t * 64; ss = 0.f;
  for (int d = 0; d < 64; ++d) { float x = p[d]; ss += x * x; }
  sc = __builtin_amdgcn_rcpf(__builtin_amdgcn_sqrtf(ss) + 1e-8f);
  for (int d = 0; d < 64; ++d) ws[OFF_KNF + t * 64 + d] = f2b(p[d] * sc);

  p = dk + t * 64; ss = 0.f;
  for (int d = 0; d < 64; ++d) { float x = p[d]; ss += x * x; }
  sc = __builtin_amdgcn_rcpf(__builtin_amdgcn_sqrtf(ss) + 1e-8f);
  for (int d = 0; d < 64; ++d) ws[OFF_KND + t * 64 + d] = f2b(p[d] * sc);

  p = fv + t * 64;
  for (int d = 0; d < 64; ++d) ws[OFF_VTF + h * 4096 + d * 64 + s] = f2b(p[d]);
  p = dv + t * 64;
  for (int d = 0; d < 64; ++d) ws[OFF_VTD + h * 4096 + d * 64 + s] = f2b(p[d]);
}

// ---------- fused main kernel ----------
// 1024 blocks x 256 threads; 64 rows/block; wave w == head w.
__global__ __launch_bounds__(256, 2)
void k_fused(const float* __restrict__ query, const float* __restrict__ context,
             const float* __restrict__ bq, const float* __restrict__ bg,
             const float* __restrict__ bc1, const float* __restrict__ Wc2,
             const float* __restrict__ bc2v, const float* __restrict__ bo,
             const float* __restrict__ mixl, const u16* __restrict__ ws,
             float* __restrict__ outp) {
  __shared__ u16 sX[64 * 256];      // 32 KB: ctx/query stage -> qn/attn chunks -> out_pre
  __shared__ float red_g[4][64];
  __shared__ float red_c[4][64];
  __shared__ float sA[64];          // conf*mix
  __shared__ float sB[64];          // conf*(1-mix)

  const int t = threadIdx.x;
  const int w = t >> 6;
  const int lane = t & 63;
  const int quad = lane >> 4;
  const int l16 = lane & 15;
  const int row4 = quad * 4;
  const int blk = blockIdx.x;
  char* Xb = (char*)sX;
  char* chunk = Xb + w * 8192;      // per-wave 64x64 bf16 scratch (swizzled)

  // XOR-swizzled staging: X[row][col], groups of 8 bf16, group ^= row&7
  auto stage = [&](const float* src) {
    #pragma unroll
    for (int i = 0; i < 16; ++i) {
      int e = i * 1024 + t * 4;
      float4 v = *(const float4*)(src + e);
      int row = e >> 8, col = e & 255;
      u16x4 pk;
      pk.x = f2b(v.x); pk.y = f2b(v.y); pk.z = f2b(v.z); pk.w = f2b(v.w);
      *(u16x4*)(Xb + row * 512 + ((((col >> 3) ^ (row & 7)) << 4) | ((col & 7) << 1))) = pk;
    }
  };
  auto ldA = [&](int row, int kb) {  // A-frag: m=row, k=kb..kb+7 (kb multiple of 8)
    return *(const bf16x8*)(Xb + row * 512 + ((((kb >> 3) ^ (row & 7)) << 4)));
  };
  auto ldC = [&](int row, int kb) {  // A-frag from per-wave chunk
    return *(const bf16x8*)(chunk + row * 128 + ((((kb >> 3) ^ (row & 7)) << 4)));
  };
  auto cwr = [&](int row, int col, u16 v) {  // scalar bf16 write into chunk
    *(u16*)(chunk + row * 128 + (((((col >> 3) ^ (row & 7)) << 3) | (col & 7)) << 1)) = v;
  };

  const f32x4 vzero = {0.f, 0.f, 0.f, 0.f};

  // ===== Phase 1: context -> mix & conf =====
  stage(context + (size_t)blk * 16384);
  __syncthreads();

  {  // gate GEMM: tanh(ctx @ Wg^T + bg), row-mean
    f32x4 acc[4][4];
    #pragma unroll
    for (int mt = 0; mt < 4; ++mt)
      #pragma unroll
      for (int nt = 0; nt < 4; ++nt) acc[mt][nt] = vzero;
    const u16* WB = ws + OFF_WG + (w * 64 + l16) * 256;
    #pragma unroll
    for (int kk = 0; kk < 8; ++kk) {
      int kb = kk * 32 + quad * 8;
      bf16x8 a0 = ldA(l16, kb), a1 = ldA(16 + l16, kb), a2 = ldA(32 + l16, kb), a3 = ldA(48 + l16, kb);
      #pragma unroll
      for (int nt = 0; nt < 4; ++nt) {
        bf16x8 b = *(const bf16x8*)(WB + nt * 4096 + kb);
        acc[0][nt] = MFMA16(a0, b, acc[0][nt]);
        acc[1][nt] = MFMA16(a1, b, acc[1][nt]);
        acc[2][nt] = MFMA16(a2, b, acc[2][nt]);
        acc[3][nt] = MFMA16(a3, b, acc[3][nt]);
      }
    }
    float bgv[4];
    #pragma unroll
    for (int nt = 0; nt < 4; ++nt) bgv[nt] = bg[w * 64 + nt * 16 + l16];
    #pragma unroll
    for (int mt = 0; mt < 4; ++mt)
      #pragma unroll
      for (int r = 0; r < 4; ++r) {
        float s = 0.f;
        #pragma unroll
        for (int nt = 0; nt < 4; ++nt) s += ftanh(acc[mt][nt][r] + bgv[nt]);
        s = sum16(s);
        if (l16 == 0) red_g[w][mt * 16 + row4 + r] = s;
      }
  }
  {  // conf GEMM: tanh(ctx @ Wc1^T + bc1) . Wc2
    f32x4 acc[4][2];
    #pragma unroll
    for (int mt = 0; mt < 4; ++mt) { acc[mt][0] = vzero; acc[mt][1] = vzero; }
    const u16* WB = ws + OFF_WC1 + (w * 32 + l16) * 256;
    #pragma unroll
    for (int kk = 0; kk < 8; ++kk) {
      int kb = kk * 32 + quad * 8;
      bf16x8 a0 = ldA(l16, kb), a1 = ldA(16 + l16, kb), a2 = ldA(32 + l16, kb), a3 = ldA(48 + l16, kb);
      #pragma unroll
      for (int nt = 0; nt < 2; ++nt) {
        bf16x8 b = *(const bf16x8*)(WB + nt * 4096 + kb);
        acc[0][nt] = MFMA16(a0, b, acc[0][nt]);
        acc[1][nt] = MFMA16(a1, b, acc[1][nt]);
        acc[2][nt] = MFMA16(a2, b, acc[2][nt]);
        acc[3][nt] = MFMA16(a3, b, acc[3][nt]);
      }
    }
    float bcv[2], wcv[2];
    #pragma unroll
    for (int nt = 0; nt < 2; ++nt) {
      int n = w * 32 + nt * 16 + l16;
      bcv[nt] = bc1[n]; wcv[nt] = Wc2[n];
    }
    #pragma unroll
    for (int mt = 0; mt < 4; ++mt)
      #pragma unroll
      for (int r = 0; r < 4; ++r) {
        float s = 0.f;
        #pragma unroll
        for (int nt = 0; nt < 2; ++nt) s += ftanh(acc[mt][nt][r] + bcv[nt]) * wcv[nt];
        s = sum16(s);
        if (l16 == 0) red_c[w][mt * 16 + row4 + r] = s;
      }
  }
  __syncthreads();
  if (t < 64) {
    float g = (red_g[0][t] + red_g[1][t] + red_g[2][t] + red_g[3][t]) * (1.f / 256.f);
    float mix = fsig(mixl[0] + g);
    float conf = fsig(red_c[0][t] + red_c[1][t] + red_c[2][t] + red_c[3][t] + bc2v[0]);
    sA[t] = conf * mix;
    sB[t] = conf - conf * mix;
  }
  __syncthreads();

  // ===== Phase 2: query projection + dual-tier attention =====
  stage(query + (size_t)blk * 16384);
  __syncthreads();

  f32x4 qa[4][4];
  {
    #pragma unroll
    for (int mt = 0; mt < 4; ++mt)
      #pragma unroll
      for (int nt = 0; nt < 4; ++nt) qa[mt][nt] = vzero;
    const u16* WB = ws + OFF_WQ + (w * 64 + l16) * 256;
    #pragma unroll
    for (int kk = 0; kk < 8; ++kk) {
      int kb = kk * 32 + quad * 8;
      bf16x8 a0 = ldA(l16, kb), a1 = ldA(16 + l16, kb), a2 = ldA(32 + l16, kb), a3 = ldA(48 + l16, kb);
      #pragma unroll
      for (int nt = 0; nt < 4; ++nt) {
        bf16x8 b = *(const bf16x8*)(WB + nt * 4096 + kb);
        qa[0][nt] = MFMA16(a0, b, qa[0][nt]);
        qa[1][nt] = MFMA16(a1, b, qa[1][nt]);
        qa[2][nt] = MFMA16(a2, b, qa[2][nt]);
        qa[3][nt] = MFMA16(a3, b, qa[3][nt]);
      }
    }
    float bqv[4];
    #pragma unroll
    for (int nt = 0; nt < 4; ++nt) bqv[nt] = bq[w * 64 + nt * 16 + l16];
    #pragma unroll
    for (int mt = 0; mt < 4; ++mt)
      #pragma unroll
      for (int nt = 0; nt < 4; ++nt)
        #pragma unroll
        for (int r = 0; r < 4; ++r) qa[mt][nt][r] += bqv[nt];
  }
  float scl[4][4];
  #pragma unroll
  for (int mt = 0; mt < 4; ++mt)
    #pragma unroll
    for (int r = 0; r < 4; ++r) {
      float ss = 0.f;
      #pragma unroll
      for (int nt = 0; nt < 4; ++nt) ss += qa[mt][nt][r] * qa[mt][nt][r];
      ss = sum16(ss);
      scl[mt][r] = __builtin_amdgcn_rcpf(__builtin_amdgcn_sqrtf(ss) + 1e-8f);
    }
  __syncthreads();  // all waves done reading X before chunks overwrite it

  // write normalized q (bf16) into per-wave chunk
  #pragma unroll
  for (int mt = 0; mt < 4; ++mt)
    #pragma unroll
    for (int r = 0; r < 4; ++r) {
      int row = mt * 16 + row4 + r;
      #pragma unroll
      for (int nt = 0; nt < 4; ++nt)
        cwr(row, nt * 16 + l16, f2b(qa[mt][nt][r] * scl[mt][r]));
    }

  // both tiers' similarity GEMMs (qn still live in chunk)
  f32x4 sf[4][4], sd[4][4];
  #pragma unroll
  for (int mt = 0; mt < 4; ++mt)
    #pragma unroll
    for (int nt = 0; nt < 4; ++nt) { sf[mt][nt] = vzero; sd[mt][nt] = vzero; }
  {
    const u16* knF = ws + OFF_KNF + w * 4096;
    const u16* knD = ws + OFF_KND + w * 4096;
    #pragma unroll
    for (int kk = 0; kk < 2; ++kk) {
      int kb = kk * 32 + quad * 8;
      bf16x8 a0 = ldC(l16, kb), a1 = ldC(16 + l16, kb), a2 = ldC(32 + l16, kb), a3 = ldC(48 + l16, kb);
      #pragma unroll
      for (int nt = 0; nt < 4; ++nt) {
        bf16x8 bF = *(const bf16x8*)(knF + (nt * 16 + l16) * 64 + kb);
        bf16x8 bD = *(const bf16x8*)(knD + (nt * 16 + l16) * 64 + kb);
        sf[0][nt] = MFMA16(a0, bF, sf[0][nt]);
        sf[1][nt] = MFMA16(a1, bF, sf[1][nt]);
        sf[2][nt] = MFMA16(a2, bF, sf[2][nt]);
        sf[3][nt] = MFMA16(a3, bF, sf[3][nt]);
        sd[0][nt] = MFMA16(a0, bD, sd[0][nt]);
        sd[1][nt] = MFMA16(a1, bD, sd[1][nt]);
        sd[2][nt] = MFMA16(a2, bD, sd[2][nt]);
        sd[3][nt] = MFMA16(a3, bD, sd[3][nt]);
      }
    }
  }

  f32x4 oacc[4][4];
  {  // ---- fast tier: softmax (sims bounded by 1, no max-sub needed) + PV ----
    #pragma unroll
    for (int mt = 0; mt < 4; ++mt)
      #pragma unroll
      for (int r = 0; r < 4; ++r) {
        float rs = 0.f;
        #pragma unroll
        for (int nt = 0; nt < 4; ++nt) { float e = __expf(sf[mt][nt][r]); sf[mt][nt][r] = e; rs += e; }
        rs = sum16(rs);
        float inv = __builtin_amdgcn_rcpf(rs);
        int row = mt * 16 + row4 + r;
        #pragma unroll
        for (int nt = 0; nt < 4; ++nt) cwr(row, nt * 16 + l16, f2b(sf[mt][nt][r] * inv));
      }
    f32x4 pv[4][4];
    #pragma unroll
    for (int mt = 0; mt < 4; ++mt)
      #pragma unroll
      for (int nt = 0; nt < 4; ++nt) pv[mt][nt] = vzero;
    const u16* vT = ws + OFF_VTF + w * 4096;
    #pragma unroll
    for (int kk = 0; kk < 2; ++kk) {
      int kb = kk * 32 + quad * 8;
      bf16x8 a0 = ldC(l16, kb), a1 = ldC(16 + l16, kb), a2 = ldC(32 + l16, kb), a3 = ldC(48 + l16, kb);
      #pragma unroll
      for (int nt = 0; nt < 4; ++nt) {
        bf16x8 b = *(const bf16x8*)(vT + (nt * 16 + l16) * 64 + kb);
        pv[0][nt] = MFMA16(a0, b, pv[0][nt]);
        pv[1][nt] = MFMA16(a1, b, pv[1][nt]);
        pv[2][nt] = MFMA16(a2, b, pv[2][nt]);
        pv[3][nt] = MFMA16(a3, b, pv[3][nt]);
      }
    }
    #pragma unroll
    for (int mt = 0; mt < 4; ++mt)
      #pragma unroll
      for (int r = 0; r < 4; ++r) {
        float m_ = sA[mt * 16 + row4 + r];
        #pragma unroll
        for (int nt = 0; nt < 4; ++nt) oacc[mt][nt][r] = m_ * pv[mt][nt][r];
      }
  }
  {  // ---- deep tier ----
    #pragma unroll
    for (int mt = 0; mt < 4; ++mt)
      #pragma unroll
      for (int r = 0; r < 4; ++r) {
        float rs = 0.f;
        #pragma unroll
        for (int nt = 0; nt < 4; ++nt) { float e = __expf(sd[mt][nt][r]); sd[mt][nt][r] = e; rs += e; }
        rs = sum16(rs);
        float inv = __builtin_amdgcn_rcpf(rs);
        int row = mt * 16 + row4 + r;
        #pragma unroll
        for (int nt = 0; nt < 4; ++nt) cwr(row, nt * 16 + l16, f2b(sd[mt][nt][r] * inv));
      }
    f32x4 pv[4][4];
    #pragma unroll
    for (int mt = 0; mt < 4; ++mt)
      #pragma unroll
      for (int nt = 0; nt < 4; ++nt) pv[mt][nt] = vzero;
    const u16* vT = ws + OFF_VTD + w * 4096;
    #pragma unroll
    for (int kk = 0; kk < 2; ++kk) {
      int kb = kk * 32 + quad * 8;
      bf16x8 a0 = ldC(l16, kb), a1 = ldC(16 + l16, kb), a2 = ldC(32 + l16, kb), a3 = ldC(48 + l16, kb);
      #pragma unroll
      for (int nt = 0; nt < 4; ++nt) {
        bf16x8 b = *(const bf16x8*)(vT + (nt * 16 + l16) * 64 + kb);
        pv[0][nt] = MFMA16(a0, b, pv[0][nt]);
        pv[1][nt] = MFMA16(a1, b, pv[1][nt]);
        pv[2][nt] = MFMA16(a2, b, pv[2][nt]);
        pv[3][nt] = MFMA16(a3, b, pv[3][nt]);
      }
    }
    #pragma unroll
    for (int mt = 0; mt < 4; ++mt)
      #pragma unroll
      for (int r = 0; r < 4; ++r) {
        float m_ = sB[mt * 16 + row4 + r];
        #pragma unroll
        for (int nt = 0; nt < 4; ++nt) oacc[mt][nt][r] += m_ * pv[mt][nt][r];
      }
  }

  // ===== Phase 3: out_pre -> X, final GEMM (Wo) =====
  __syncthreads();  // all chunk reads done before X reused as out_pre
  #pragma unroll
  for (int mt = 0; mt < 4; ++mt)
    #pragma unroll
    for (int r = 0; r < 4; ++r) {
      int row = mt * 16 + row4 + r;
      #pragma unroll
      for (int nt = 0; nt < 4; ++nt) {
        int col = w * 64 + nt * 16 + l16;
        *(u16*)(Xb + row * 512 + (((((col >> 3) ^ (row & 7)) << 3) | (col & 7)) << 1)) =
            f2b(oacc[mt][nt][r]);
      }
    }
  __syncthreads();

  {
    f32x4 o[4][4];
    #pragma unroll
    for (int mt = 0; mt < 4; ++mt)
      #pragma unroll
      for (int nt = 0; nt < 4; ++nt) o[mt][nt] = vzero;
    const u16* WB = ws + OFF_WO + (w * 64 + l16) * 256;
    #pragma unroll
    for (int kk = 0; kk < 8; ++kk) {
      int kb = kk * 32 + quad * 8;
      bf16x8 a0 = ldA(l16, kb), a1 = ldA(16 + l16, kb), a2 = ldA(32 + l16, kb), a3 = ldA(48 + l16, kb);
      #pragma unroll
      for (int nt = 0; nt < 4; ++nt) {
        bf16x8 b = *(const bf16x8*)(WB + nt * 4096 + kb);
        o[0][nt] = MFMA16(a0, b, o[0][nt]);
        o[1][nt] = MFMA16(a1, b, o[1][nt]);
        o[2][nt] = MFMA16(a2, b, o[2][nt]);
        o[3][nt] = MFMA16(a3, b, o[3][nt]);
      }
    }
    float bov[4];
    #pragma unroll
    for (int nt = 0; nt < 4; ++nt) bov[nt] = bo[w * 64 + nt * 16 + l16];
    float* dst = outp + (size_t)blk * 16384;
    #pragma unroll
    for (int mt = 0; mt < 4; ++mt)
      #pragma unroll
      for (int r = 0; r < 4; ++r) {
        int row = mt * 16 + row4 + r;
        #pragma unroll
        for (int nt = 0; nt < 4; ++nt)
          dst[row * 256 + w * 64 + nt * 16 + l16] = o[mt][nt][r] + bov[nt];
      }
  }
}

extern "C" void kernel_launch(void* const* d_in, const int* in_sizes, int n_in,
                              void* d_out, int out_size, void* d_ws, size_t ws_size,
                              hipStream_t stream) {
  const float* query   = (const float*)d_in[0];
  const float* context = (const float*)d_in[1];
  const float* fk      = (const float*)d_in[2];
  const float* fv      = (const float*)d_in[3];
  const float* dk      = (const float*)d_in[4];
  const float* dv      = (const float*)d_in[5];
  const float* Wq      = (const float*)d_in[6];
  const float* bq      = (const float*)d_in[7];
  const float* Wg      = (const float*)d_in[8];
  const float* bg      = (const float*)d_in[9];
  const float* Wc1     = (const float*)d_in[10];
  const float* bc1     = (const float*)d_in[11];
  const float* Wc2     = (const float*)d_in[12];
  const float* bc2     = (const float*)d_in[13];
  const float* Wo      = (const float*)d_in[14];
  const float* bo      = (const float*)d_in[15];
  // d_in[16] Ws, d_in[17] bs: dead code (surprise is deleted)
  const float* mixl    = (const float*)d_in[18];
  u16* ws = (u16*)d_ws;
  float* outp = (float*)d_out;

  k_convert<<<256, 256, 0, stream>>>(Wq, Wg, Wc1, Wo, ws);
  k_prep<<<4, 64, 0, stream>>>(fk, fv, dk, dv, ws);
  k_fused<<<1024, 256, 0, stream>>>(query, context, bq, bg, bc1, Wc2, bc2, bo,
                                    mixl, ws, outp);
}